// Round 11
// baseline (157.107 us; speedup 1.0000x reference)
//
#include <hip/hip_runtime.h>
#include <hip/hip_bf16.h>
#include <math.h>

#define Bg   128
#define Nn   64
#define Tt   256
#define INF  320      // Nn + Tt
#define Hd   256
#define OUTD 128
#define Ee   2016     // Nn*(Nn-1)/2
#define TOTE (Bg*Ee)  // 258048
#define SCOLS 576     // padded 514 -> 9*64 so GEMM2 tiles exactly
#define MROWS 8192    // Bg*Nn

typedef __attribute__((ext_vector_type(8))) short bf16x8;
typedef __attribute__((ext_vector_type(4))) float f32x4;

static __device__ __forceinline__ ushort f2bf(float v) {
    __hip_bfloat16 h = __float2bfloat16(v);
    return *(ushort*)&h;
}

// ================= prep: WgT->bf16, WcatT->bf16, ebias, LUT, red init =================
// Weights stored TRANSPOSED row-major: WgbT[n][k] (256x320), WcatT[n][k] (576x256).
#define CVT_N (INF * Hd)                  // 81920
#define PACK_N (Hd * SCOLS)               // 147456
__global__ void k_prep(const float* __restrict__ Wg, const float* __restrict__ Wm,
                       const float* __restrict__ Wv, const float* __restrict__ Ww,
                       const float* __restrict__ bm, const float* __restrict__ bv,
                       const float* __restrict__ bw,
                       ushort* __restrict__ WgbT, ushort* __restrict__ WcatT,
                       float* __restrict__ ebias, int2* __restrict__ lut,
                       unsigned* __restrict__ red) {
    int idx = blockIdx.x * 256 + threadIdx.x;
    if (idx == 0) { red[0] = 0u; red[1] = 0u; }
    if (idx < CVT_N) {
        int n = idx / INF, k = idx - n * INF;
        WgbT[idx] = f2bf(Wg[k * Hd + n]);
        return;
    }
    idx -= CVT_N;
    if (idx < PACK_N) {
        int n = idx / Hd, k = idx - n * Hd;   // n = output col, k = reduction
        float v = 0.f;
        if (n < 128)       v = Wm[k * 128 + n];
        else if (n < 256)  v = Wm[(256 + k) * 128 + (n - 128)];
        else if (n < 384)  v = Wv[k * 128 + (n - 256)];
        else if (n < 512)  v = Wv[(256 + k) * 128 + (n - 384)];
        else if (n == 512) v = Ww[k];
        else if (n == 513) v = Ww[256 + k];
        WcatT[idx] = f2bf(v);
        return;
    }
    idx -= PACK_N;
    if (idx < SCOLS) {
        float e = 0.f;
        if (idx < 128)                    e = bm[idx];
        else if (idx >= 256 && idx < 384) e = bv[idx - 256];
        else if (idx == 512)              e = bw[0];
        ebias[idx] = e;
        return;
    }
    idx -= SCOLS;
    if (idx >= Ee) return;
    int r = 0;
    while ((r + 1) * (127 - (r + 1)) / 2 <= idx) ++r;
    int c = r + 1 + (idx - r * (127 - r) / 2);
    lut[idx] = make_int2(r, c);
}

// ================= prefix-mean aggregation: LDS-tiled coalesced scan =================
// grid (128 graphs, 5 f-tiles of 64). (R8-proven)
__global__ __launch_bounds__(256) void k_agg(const float* __restrict__ topo,
                                             const float* __restrict__ temp,
                                             ushort* __restrict__ agg) {
    __shared__ float T[64 * 65];
    const int b = blockIdx.x, ft = blockIdx.y;
    const int tid = threadIdx.x;
    const int row = tid >> 2, seg = tid & 3;
    const float* src = (ft == 0) ? (topo + (size_t)(b * Nn + row) * Nn)
                                 : (temp + (size_t)(b * Nn + row) * Tt + (ft - 1) * 64);
    #pragma unroll
    for (int i = 0; i < 4; ++i) {
        float4 v = *(const float4*)(src + seg * 16 + i * 4);
        float* d = &T[row * 65 + seg * 16 + i * 4];
        d[0] = v.x; d[1] = v.y; d[2] = v.z; d[3] = v.w;
    }
    __syncthreads();
    const int w = tid >> 6, lane = tid & 63;
    #pragma unroll
    for (int k = 0; k < 16; ++k) {
        int f = w * 16 + k;
        float x = T[lane * 65 + f];
        float incl = x;
        #pragma unroll
        for (int o = 1; o < 64; o <<= 1) {
            float t = __shfl_up(incl, o);
            if (lane >= o) incl += t;
        }
        float excl = incl - x;
        T[lane * 65 + f] = lane ? excl * __builtin_amdgcn_rcpf((float)lane) : 0.f;
    }
    __syncthreads();
    const int node = tid >> 2, f0 = (tid & 3) * 16;
    ushort tmp[16];
    #pragma unroll
    for (int i = 0; i < 16; ++i) tmp[i] = f2bf(T[node * 65 + f0 + i]);
    ushort* dst = agg + (size_t)(b * Nn + node) * INF + ft * 64 + f0;
    *(uint4*)dst = *(uint4*)tmp;
    *(uint4*)(dst + 8) = *(uint4*)(tmp + 8);
}

// ================= bf16 MFMA GEMM, 64x64 tile, BK=64, B pre-transposed (R8) =================
__global__ __launch_bounds__(256) void k_gemm_mfma(const ushort* __restrict__ A,
                                                   const ushort* __restrict__ BT,
                                                   const float* __restrict__ bias,
                                                   ushort* __restrict__ Cb,
                                                   float* __restrict__ Cf,
                                                   int N, int K, int relu, int transC) {
    __shared__ ushort Asl[64 * 72];
    __shared__ ushort Bsl[64 * 72];   // [n][k]
    const int tid = threadIdx.x;
    const int w = tid >> 6, lane = tid & 63;
    const int quad = lane >> 4, r16 = lane & 15;
    const int m0 = blockIdx.y * 64, n0 = blockIdx.x * 64;
    const int row = tid >> 2, seg = tid & 3;
    f32x4 acc[4] = {};

    for (int k0 = 0; k0 < K; k0 += 64) {
        const ushort* ap = A + (size_t)(m0 + row) * K + k0 + seg * 16;
        uint4 a0 = ((const uint4*)ap)[0];
        uint4 a1 = ((const uint4*)ap)[1];
        *(uint4*)(Asl + row * 72 + seg * 16)     = a0;
        *(uint4*)(Asl + row * 72 + seg * 16 + 8) = a1;
        const ushort* bp = BT + (size_t)(n0 + row) * K + k0 + seg * 16;
        uint4 b0 = ((const uint4*)bp)[0];
        uint4 b1 = ((const uint4*)bp)[1];
        *(uint4*)(Bsl + row * 72 + seg * 16)     = b0;
        *(uint4*)(Bsl + row * 72 + seg * 16 + 8) = b1;
        __syncthreads();

        bf16x8 af0 = *(const bf16x8*)(Asl + (w * 16 + r16) * 72 + quad * 8);
        bf16x8 af1 = *(const bf16x8*)(Asl + (w * 16 + r16) * 72 + 32 + quad * 8);
        #pragma unroll
        for (int ns = 0; ns < 4; ++ns) {
            bf16x8 bf0 = *(const bf16x8*)(Bsl + (ns * 16 + r16) * 72 + quad * 8);
            bf16x8 bf1 = *(const bf16x8*)(Bsl + (ns * 16 + r16) * 72 + 32 + quad * 8);
            acc[ns] = __builtin_amdgcn_mfma_f32_16x16x32_bf16(af0, bf0, acc[ns], 0, 0, 0);
            acc[ns] = __builtin_amdgcn_mfma_f32_16x16x32_bf16(af1, bf1, acc[ns], 0, 0, 0);
        }
        __syncthreads();
    }

    const int row0 = m0 + w * 16 + quad * 4;
    #pragma unroll
    for (int ns = 0; ns < 4; ++ns) {
        f32x4 a = acc[ns];
        int col = n0 + ns * 16 + r16;
        float bb = bias ? bias[col] : 0.f;
        float vv[4];
        #pragma unroll
        for (int i = 0; i < 4; ++i) {
            float v = a[i] + bb;
            if (relu) v = fmaxf(v, 0.f);
            vv[i] = v;
        }
        if (transC) {
            *(float4*)(Cf + (size_t)col * MROWS + row0) = make_float4(vv[0], vv[1], vv[2], vv[3]);
        } else {
            #pragma unroll
            for (int i = 0; i < 4; ++i) {
                int row2 = row0 + i;
                if (Cb) Cb[(size_t)row2 * N + col] = f2bf(vv[i]);
                else    Cf[(size_t)row2 * N + col] = vv[i];
            }
        }
    }
}

// ================= edge partials: t-sliced, zero trans-overcompute =================
// 2560 blocks = 128 graphs x 10 pair-blocks x 2 t-slices. LDS [4][16][68] = 17.4 KB.
// p<6: off-diag group pair, 256 active pairs. p>=6: diag group p-6, 120 active
// (tri-decoded; waves 2-3 exit). Writes partial[ts][edge] (every edge covered).
static __device__ __forceinline__ float eterm(float pm, float qm, float pv, float qv) {
    float m = pm + qm;
    float x = pv + qv;
    float sp = fmaxf(x, 0.f) + __logf(1.f + __expf(-fabsf(x)));
    return m * m * __builtin_amdgcn_rcpf(sp + 1.01e-6f);
}

__global__ __launch_bounds__(256) void k_edge5(const float* __restrict__ ST,
                                               float* __restrict__ partial) {
    __shared__ float L[4][16][68];
    const int blk = blockIdx.x;
    const int ts = blk & 1;
    const int p  = (blk >> 1) % 10;
    const int b  = blk / 20;
    const int toff = ts * 64;
    const int tid = threadIdx.x;
    const int G0v[10] = {0,0,0,1,1,2, 0,1,2,3};
    const int G1v[10] = {1,2,3,2,3,3, 0,1,2,3};
    const int g0 = G0v[p], g1 = G1v[p];

    // stage: arr 0=Pm(g0) 1=Qm(g1) 2=Pv(g0) 3=Qv(g1), 64 t each
    #pragma unroll
    for (int rep = 0; rep < 4; ++rep) {
        int it = tid + 256 * rep;              // 0..1023
        int arr = it >> 8;
        int idx2 = it & 255;
        int c = idx2 >> 2, nq = idx2 & 3;      // t-row, node-quad
        int g = (arr & 1) ? g1 : g0;
        float4 v = *(const float4*)&ST[(size_t)(arr * 128 + toff + c) * MROWS + b * 64 + g * 16 + nq * 4];
        L[arr][nq * 4 + 0][c] = v.x;
        L[arr][nq * 4 + 1][c] = v.y;
        L[arr][nq * 4 + 2][c] = v.z;
        L[arr][nq * 4 + 3][c] = v.w;
    }
    __syncthreads();

    int i, j;
    bool act;
    if (p < 6) {
        i = tid >> 4; j = tid & 15; act = true;
    } else {
        act = tid < 120;
        i = 0; j = 0;
        if (act) {
            int rem = tid;
            while (rem >= 15 - i) { rem -= 15 - i; ++i; }
            j = i + 1 + rem;
        }
    }

    if (act) {
        float acc = 0.f;
        #pragma unroll 4
        for (int t = 0; t < 64; t += 4) {
            float4 mi = *(const float4*)&L[0][i][t];
            float4 mj = *(const float4*)&L[1][j][t];
            float4 vi = *(const float4*)&L[2][i][t];
            float4 vj = *(const float4*)&L[3][j][t];
            acc += eterm(mi.x, mj.x, vi.x, vj.x);
            acc += eterm(mi.y, mj.y, vi.y, vj.y);
            acc += eterm(mi.z, mj.z, vi.z, vj.z);
            acc += eterm(mi.w, mj.w, vi.w, vj.w);
        }
        int ni = g0 * 16 + i, nj = g1 * 16 + j;
        partial[(size_t)ts * TOTE + b * Ee + (ni * (127 - ni)) / 2 + (nj - ni - 1)] = acc;
    }
}

// ================= finalize: sim*exp(logit) + denominator atomic =================
// TOTE = 1008 * 256 exactly.
__global__ __launch_bounds__(256) void k_fin(const float* __restrict__ partial,
                                             const float* __restrict__ ST,
                                             const int2* __restrict__ lut,
                                             const float* __restrict__ gu,
                                             float* __restrict__ numer,
                                             unsigned* __restrict__ red) {
    __shared__ float sm[256];
    int e = blockIdx.x * 256 + threadIdx.x;
    int b = e / Ee, el = e - b * Ee;
    int2 rc = lut[el];
    float acc = partial[e] + partial[TOTE + e];
    float se = __expf(acc * (-1.f / 256.f));   // exp(-0.5*acc/128)
    float wr = ST[(size_t)512 * MROWS + b * 64 + rc.x]
             + ST[(size_t)513 * MROWS + b * 64 + rc.y];   // bw folded into row 512
    float w  = __builtin_amdgcn_rcpf(1.f + __expf(-wr));
    float g  = -__logf(-__logf(gu[e]));
    float en = __expf((w + g) * 2.0f);         // exp(logit), logit <= ~36: safe
    numer[e] = se * en;
    sm[threadIdx.x] = en; __syncthreads();
    for (int s = 128; s; s >>= 1) {
        if (threadIdx.x < s) sm[threadIdx.x] += sm[threadIdx.x + s];
        __syncthreads();
    }
    if (!threadIdx.x) atomicAdd((float*)&red[1], sm[0]);
}

// ================= final scatter (also zero-fills) =================
__global__ void k_out(const float* __restrict__ numer, const unsigned* __restrict__ red,
                      float* __restrict__ out) {
    int idx = blockIdx.x * 256 + threadIdx.x;
    if (idx >= Bg * Nn * Nn) return;
    int b = idx >> 12;
    int rem = idx & 4095;
    int r = rem >> 6, c = rem & 63;
    float v = 0.f;
    if (c > r) {
        int e = b * Ee + (r * (127 - r)) / 2 + (c - r - 1);
        float Sinv = __builtin_amdgcn_rcpf(((const float*)red)[1]);
        v = numer[e] * Sinv;
    }
    out[idx] = v;
}

extern "C" void kernel_launch(void* const* d_in, const int* in_sizes, int n_in,
                              void* d_out, int out_size, void* d_ws, size_t ws_size,
                              hipStream_t stream) {
    const float* topo = (const float*)d_in[0];
    const float* temp = (const float*)d_in[1];
    const float* gu   = (const float*)d_in[2];
    const float* Wg   = (const float*)d_in[3];
    const float* bg   = (const float*)d_in[4];
    const float* Wm   = (const float*)d_in[5];
    const float* bm   = (const float*)d_in[6];
    const float* Wv   = (const float*)d_in[7];
    const float* bv   = (const float*)d_in[8];
    const float* Ww   = (const float*)d_in[9];
    const float* bw   = (const float*)d_in[10];
    float* out = (float*)d_out;

    char* ws = (char*)d_ws;
    size_t off = 0;
    auto carve = [&](size_t bytes) { char* p = ws + off; off = (off + bytes + 255) & ~(size_t)255; return p; };

    // r1 hosts aggb (bf16, 5.2 MB) pre-GEMM1, then S_T[576][8192] f32 (18.9 MB).
    char*   r1    = carve((size_t)SCOLS * MROWS * 4);
    float*  ST    = (float*)r1;
    ushort* aggb  = (ushort*)r1;
    ushort* hb    = (ushort*)carve((size_t)MROWS * Hd * 2);      // 4.19 MB
    ushort* WgbT  = (ushort*)carve((size_t)CVT_N * 2);           // 0.16 MB
    ushort* WcatT = (ushort*)carve((size_t)PACK_N * 2);          // 0.29 MB
    float*  ebias = (float*)carve((size_t)SCOLS * 4);
    float*  part  = (float*)carve((size_t)2 * TOTE * 4);         // 2.06 MB
    float*  numer = (float*)carve((size_t)TOTE * 4);             // 1.03 MB
    int2*   lut   = (int2*)carve((size_t)Ee * 8);
    unsigned* red = (unsigned*)carve(256);

    k_prep<<<(CVT_N + PACK_N + SCOLS + Ee + 255) / 256, 256, 0, stream>>>(
        Wg, Wm, Wv, Ww, bm, bv, bw, WgbT, WcatT, ebias, lut, red);
    k_agg<<<dim3(Bg, INF / 64), 256, 0, stream>>>(topo, temp, aggb);
    // GEMM1: hb[8192,256] = relu(aggb[8192,320] @ WgbT^T + bg)
    k_gemm_mfma<<<dim3(Hd / 64, MROWS / 64), 256, 0, stream>>>(
        aggb, WgbT, bg, hb, nullptr, Hd, INF, 1, 0);
    // GEMM2: ST[576][8192] = (hb[8192,256] @ WcatT^T + ebias)^T
    k_gemm_mfma<<<dim3(SCOLS / 64, MROWS / 64), 256, 0, stream>>>(
        hb, WcatT, ebias, nullptr, ST, SCOLS, Hd, 0, 1);
    k_edge5<<<Bg * 20, 256, 0, stream>>>(ST, part);
    k_fin<<<TOTE / 256, 256, 0, stream>>>(part, ST, lut, gu, numer, red);
    k_out<<<(Bg * Nn * Nn + 255) / 256, 256, 0, stream>>>(numer, red, out);
}